// Round 3
// baseline (189.626 us; speedup 1.0000x reference)
//
#include <hip/hip_runtime.h>
#include <cstdint>

// Attention B=4, S=4096, WORD=512, ED=64, fp32 io. R3.
// attn: no-max softmax (P=exp2(s), safe: |s|<~13 << 127), key-split waves,
// direct global->VGPR MFMA frags (L2-resident), shuffle-based P exchange,
// K-split 2 across blocks + combine. qkv: single-barrier, Wt frags from L2.

typedef __bf16 bf16x8 __attribute__((ext_vector_type(8)));
typedef float f32x4 __attribute__((ext_vector_type(4)));
typedef float f32x16 __attribute__((ext_vector_type(16)));

#define SCALEQ 0.18033688011112042f  // log2(e)/sqrt(64)

// ws layout (bytes)
#define WT_OFF 0u          // bf16 Wt[3][64][512]        = 192 KB
#define Q_OFF  262144u     // bf16 Q [16384][64] scaled  = 2 MB
#define K_OFF  2359296u    // bf16 K [16384][64]         = 2 MB
#define VT_OFF 4456448u    // bf16 Vt[4][64][4096]       = 2 MB
#define L_OFF  6553600u    // f32 [2][16384]             = 128 KB
#define OP_OFF 6684672u    // f32 [2][16384][64]         = 8 MB (ends ~14.7MB)

__device__ __forceinline__ unsigned short bf16_1(float a) {
  unsigned ua = __builtin_bit_cast(unsigned, a);
  ua += 0x7FFFu + ((ua >> 16) & 1u);
  return (unsigned short)(ua >> 16);
}
__device__ __forceinline__ unsigned pk_bf16(float a, float b) {
  unsigned ua = __builtin_bit_cast(unsigned, a);
  unsigned ub = __builtin_bit_cast(unsigned, b);
  ua += 0x7FFFu + ((ua >> 16) & 1u);
  ub += 0x7FFFu + ((ub >> 16) & 1u);
  return (ua >> 16) | (ub & 0xFFFF0000u);
}
// round-half-up bf16 pack of (lo,hi) in ONE v_perm + 2 adds
__device__ __forceinline__ unsigned pkru(float lo, float hi) {
  unsigned a = __builtin_bit_cast(unsigned, lo) + 0x8000u;
  unsigned b = __builtin_bit_cast(unsigned, hi) + 0x8000u;
  return __builtin_amdgcn_perm(b, a, 0x07060302u);  // hi.hi16 : lo.hi16
}

// ---------------- kernel 0: W fp32 [512][64] -> Wt bf16 [mat][64][512] ----
__global__ __launch_bounds__(256) void prep_w(const float* __restrict__ wq,
                                              const float* __restrict__ wk,
                                              const float* __restrict__ wv,
                                              unsigned short* __restrict__ wt) {
  unsigned tid = blockIdx.x * 256u + threadIdx.x;  // 98304
  unsigned mat = tid >> 15, rem = tid & 32767u;
  const float* w = (mat == 0) ? wq : (mat == 1) ? wk : wv;
  float v = w[rem];
  unsigned k = rem >> 6, n = rem & 63u;
  wt[mat * 32768u + n * 512u + k] = bf16_1(v);
}

// ---------------- kernel 1: QKV projection --------------------------------
// grid 512 (32 rows/block), block 256 = 4 waves = (2 row-halves x 2 n-halves)
// ONE barrier; x staged to LDS once; Wt B-frags streamed straight from L2.
__global__ __launch_bounds__(256, 2) void qkv_proj(
    const float* __restrict__ x, const unsigned short* __restrict__ wt,
    const float* __restrict__ bq, const float* __restrict__ bk,
    const float* __restrict__ bv, unsigned short* __restrict__ qo,
    unsigned short* __restrict__ ko, unsigned short* __restrict__ vto) {
  __shared__ __align__(16) char xs[32768];  // 32 rows x 512 k bf16, swizzled
  __shared__ float biasl[192];
  const unsigned t = threadIdx.x;
  const unsigned row0 = blockIdx.x * 32u;
  const unsigned w = t >> 6, lane = t & 63u, l15 = lane & 15u, quad = lane >> 4;
  const unsigned rh = w & 1u, nh = w >> 1;

  if (t < 192u) {
    unsigned mat = t >> 6, n = t & 63u;
    biasl[t] = (mat == 0) ? bq[n] : (mat == 1) ? bk[n] : bv[n];
  }
#pragma unroll
  for (int i = 0; i < 16; i++) {  // stage x: 32x512 fp32 contiguous -> bf16
    unsigned idx4 = t + 256u * (unsigned)i;
    unsigned fidx = idx4 * 4u;
    unsigned row = fidx >> 9, k = fidx & 511u, g = k >> 3;
    float4 f = *(const float4*)(x + row0 * 512u + fidx);
    int2 v = make_int2(pkru(f.x, f.y), pkru(f.z, f.w));
    *(int2*)(xs + row * 1024u + ((g ^ (row & 7u)) << 4) + (k & 7u) * 2u) = v;
  }
  __syncthreads();

  f32x4 acc[6];
#pragma unroll
  for (int i = 0; i < 6; i++) acc[i] = {0.f, 0.f, 0.f, 0.f};
  const unsigned arow = rh * 16u + l15;

  for (unsigned kc = 0; kc < 16u; kc++) {
    unsigned ag = kc * 4u + quad;
    int4 av = *(const int4*)(xs + arow * 1024u + ((ag ^ (arow & 7u)) << 4));
    bf16x8 a = __builtin_bit_cast(bf16x8, av);
#pragma unroll
    for (int nt = 0; nt < 6; nt++) {
      unsigned col = nh * 96u + (unsigned)nt * 16u + l15;
      int4 bv4 = *(const int4*)(wt + col * 512u + kc * 32u + quad * 8u);
      acc[nt] = __builtin_amdgcn_mfma_f32_16x16x32_bf16(
          a, __builtin_bit_cast(bf16x8, bv4), acc[nt], 0, 0, 0);
    }
  }
  // epilogue
  unsigned sb = row0 + rh * 16u + quad * 4u;
  unsigned vb = sb >> 12, s = sb & 4095u;
#pragma unroll
  for (int nt = 0; nt < 6; nt++) {
    unsigned col = nh * 96u + (unsigned)nt * 16u + l15;
    unsigned mat = col >> 6, n = col & 63u;
    float bb = biasl[col];
    if (mat == 0) {
#pragma unroll
      for (int r = 0; r < 4; r++)
        qo[(sb + (unsigned)r) * 64u + n] = bf16_1((acc[nt][r] + bb) * SCALEQ);
    } else if (mat == 1) {
#pragma unroll
      for (int r = 0; r < 4; r++)
        ko[(sb + (unsigned)r) * 64u + n] = bf16_1(acc[nt][r] + bb);
    } else {
      int2 pv = make_int2(pk_bf16(acc[nt][0] + bb, acc[nt][1] + bb),
                          pk_bf16(acc[nt][2] + bb, acc[nt][3] + bb));
      *(int2*)(vto + vb * 262144u + n * 4096u + s) = pv;
    }
  }
}

// ---------------- kernel 2: flash attention v3 -----------------------------
// grid 512 = ks(2) x b(4) x qt(64 of 64q); block 256 = 4 waves, each wave a
// 32-key quarter of the 128-key tile, q=64 per wave. No-max softmax.
// Frags direct from global (L2). Cross-wave key reduction via LDS atomics.
__global__ __launch_bounds__(256, 2) void attn(
    const unsigned short* __restrict__ qws, const unsigned short* __restrict__ kws,
    const unsigned short* __restrict__ vtws, float* __restrict__ lws,
    float* __restrict__ op) {
  __shared__ float red[64 * 65 + 64];  // [d][q+pad] accO sums | l[64]
  const unsigned t = threadIdx.x;
  const unsigned w = t >> 6, lane = t & 63u, l31 = lane & 31u, hl = lane >> 5;
  const unsigned ks = blockIdx.x >> 8;
  const unsigned b = (blockIdx.x >> 6) & 3u;
  const unsigned qblk = (blockIdx.x & 63u) * 64u;

  for (unsigned i = t; i < 64u * 65u + 64u; i += 256u) red[i] = 0.f;

  // Q B-frags: [qt2][kq], n=q=l31, k=d
  bf16x8 qf[2][4];
#pragma unroll
  for (int qt2 = 0; qt2 < 2; qt2++)
#pragma unroll
    for (int kq = 0; kq < 4; kq++)
      qf[qt2][kq] = __builtin_bit_cast(
          bf16x8, *(const int4*)(qws + (b * 4096u + qblk + (unsigned)qt2 * 32u + l31) * 64u +
                                 (unsigned)kq * 16u + hl * 8u));

  const unsigned short* kp =
      kws + (b * 4096u + ks * 2048u + w * 32u + l31) * 64u + hl * 8u;
  const unsigned short* vp =
      vtws + b * 262144u + l31 * 4096u + ks * 2048u + w * 32u + hl * 8u;

  f32x16 accO[4];  // [dh*2+qt2]
#pragma unroll
  for (int i = 0; i < 4; i++)
#pragma unroll
    for (int r = 0; r < 16; r++) accO[i][r] = 0.f;
  float lp0 = 0.f, lp1 = 0.f;

  bf16x8 kf[4];
#pragma unroll
  for (int kq = 0; kq < 4; kq++)
    kf[kq] = __builtin_bit_cast(bf16x8, *(const int4*)(kp + kq * 16u));
  __syncthreads();  // red[] init visible before atomics later

  for (unsigned kt = 0; kt < 16u; kt++) {
    // S^T = K * Q^T  (C: col=q=l31, row=key=(r&3)+8*(r>>2)+4*hl)
    f32x16 s0, s1;
#pragma unroll
    for (int r = 0; r < 16; r++) { s0[r] = 0.f; s1[r] = 0.f; }
#pragma unroll
    for (int kq = 0; kq < 4; kq++) {
      s0 = __builtin_amdgcn_mfma_f32_32x32x16_bf16(kf[kq], qf[0][kq], s0, 0, 0, 0);
      s1 = __builtin_amdgcn_mfma_f32_32x32x16_bf16(kf[kq], qf[1][kq], s1, 0, 0, 0);
    }
    // prefetch next K frags (reads past end stay inside ws; values unused)
#pragma unroll
    for (int kq = 0; kq < 4; kq++)
      kf[kq] = __builtin_bit_cast(
          bf16x8, *(const int4*)(kp + (kt + 1u) * 8192u + kq * 16u));
    // Vt A-frags for this tile: [dh][kqp], m=d, k=key
    bf16x8 vf[2][2];
#pragma unroll
    for (int dh = 0; dh < 2; dh++)
#pragma unroll
      for (int kqp = 0; kqp < 2; kqp++)
        vf[dh][kqp] = __builtin_bit_cast(
            bf16x8, *(const int4*)(vp + (unsigned)dh * 131072u + kt * 128u +
                                   (unsigned)kqp * 16u));
    // P = exp2(s); l partial
#pragma unroll
    for (int r = 0; r < 16; r++) {
      s0[r] = __builtin_amdgcn_exp2f(s0[r]); lp0 += s0[r];
      s1[r] = __builtin_amdgcn_exp2f(s1[r]); lp1 += s1[r];
    }
    // P -> B-operand frags via pack + lane^32 shuffle (no LDS)
    bf16x8 pf[2][2];
#pragma unroll
    for (int qt2 = 0; qt2 < 2; qt2++) {
      const f32x16& p = qt2 ? s1 : s0;
#pragma unroll
      for (int kqp = 0; kqp < 2; kqp++) {
        int rA = kqp * 8, rB = kqp * 8 + 4;
        unsigned a0 = pkru(p[rA + 0], p[rA + 1]), a1 = pkru(p[rA + 2], p[rA + 3]);
        unsigned b0 = pkru(p[rB + 0], p[rB + 1]), b1 = pkru(p[rB + 2], p[rB + 3]);
        unsigned xa0 = (unsigned)__shfl_xor((int)a0, 32);
        unsigned xa1 = (unsigned)__shfl_xor((int)a1, 32);
        unsigned xb0 = (unsigned)__shfl_xor((int)b0, 32);
        unsigned xb1 = (unsigned)__shfl_xor((int)b1, 32);
        int4 fr = hl ? make_int4((int)xb0, (int)xb1, (int)b0, (int)b1)
                     : make_int4((int)a0, (int)a1, (int)xa0, (int)xa1);
        pf[qt2][kqp] = __builtin_bit_cast(bf16x8, fr);
      }
    }
    // O^T partial += Vt * P^T over this wave's 32 keys
#pragma unroll
    for (int dh = 0; dh < 2; dh++)
#pragma unroll
      for (int qt2 = 0; qt2 < 2; qt2++)
#pragma unroll
        for (int kqp = 0; kqp < 2; kqp++)
          accO[dh * 2 + qt2] = __builtin_amdgcn_mfma_f32_32x32x16_bf16(
              vf[dh][kqp], pf[qt2][kqp], accO[dh * 2 + qt2], 0, 0, 0);
  }
  // l: fold lane^32 half, one atomic per q per wave
  lp0 += __shfl_xor(lp0, 32);
  lp1 += __shfl_xor(lp1, 32);
  if (hl == 0u) {
    atomicAdd(&red[64 * 65 + l31], lp0);
    atomicAdd(&red[64 * 65 + 32 + l31], lp1);
  }
  // accO: cross-wave (key-quarter) reduction, conflict-free banks
#pragma unroll
  for (int dh = 0; dh < 2; dh++)
#pragma unroll
    for (int qt2 = 0; qt2 < 2; qt2++)
#pragma unroll
      for (int r = 0; r < 16; r++) {
        unsigned d = (unsigned)dh * 32u + (unsigned)(r & 3) + 8u * (unsigned)(r >> 2) + 4u * hl;
        unsigned q = (unsigned)qt2 * 32u + l31;
        atomicAdd(&red[d * 65u + q], accO[dh * 2 + qt2][r]);
      }
  __syncthreads();
  // write unnormalized partials + l to global
  unsigned q = t >> 2, d0 = (t & 3u) * 16u;
  float* dst = op + ks * 1048576u + (b * 4096u + qblk + q) * 64u + d0;
#pragma unroll
  for (int i = 0; i < 4; i++) {
    float4 v;
    v.x = red[(d0 + 4u * (unsigned)i + 0u) * 65u + q];
    v.y = red[(d0 + 4u * (unsigned)i + 1u) * 65u + q];
    v.z = red[(d0 + 4u * (unsigned)i + 2u) * 65u + q];
    v.w = red[(d0 + 4u * (unsigned)i + 3u) * 65u + q];
    *(float4*)(dst + 4 * i) = v;
  }
  if (t < 64u) lws[ks * 16384u + b * 4096u + qblk + t] = red[64 * 65 + t];
}

// ---------------- kernel 3: combine 2 K-split partials ---------------------
__global__ __launch_bounds__(256) void combine(const float* __restrict__ op,
                                               const float* __restrict__ lws,
                                               float* __restrict__ out) {
  unsigned gid = blockIdx.x * 256u + threadIdx.x;  // 65536
  unsigned q = gid >> 2, c = (gid & 3u) * 16u;
  float inv = 1.0f / (lws[q] + lws[16384u + q]);
#pragma unroll
  for (int i = 0; i < 4; i++) {
    float4 o0 = *(const float4*)(op + q * 64u + c + 4u * (unsigned)i);
    float4 o1 = *(const float4*)(op + 1048576u + q * 64u + c + 4u * (unsigned)i);
    float4 r = make_float4((o0.x + o1.x) * inv, (o0.y + o1.y) * inv,
                           (o0.z + o1.z) * inv, (o0.w + o1.w) * inv);
    *(float4*)(out + q * 64u + c + 4u * (unsigned)i) = r;
  }
}

extern "C" void kernel_launch(void* const* d_in, const int* in_sizes, int n_in,
                              void* d_out, int out_size, void* d_ws,
                              size_t ws_size, hipStream_t stream) {
  const float* x = (const float*)d_in[0];
  const float* Wq = (const float*)d_in[1];
  const float* bq = (const float*)d_in[2];
  const float* Wk = (const float*)d_in[3];
  const float* bk = (const float*)d_in[4];
  const float* Wv = (const float*)d_in[5];
  const float* bv = (const float*)d_in[6];
  char* ws = (char*)d_ws;
  unsigned short* wt = (unsigned short*)(ws + WT_OFF);
  unsigned short* qb = (unsigned short*)(ws + Q_OFF);
  unsigned short* kb = (unsigned short*)(ws + K_OFF);
  unsigned short* vtb = (unsigned short*)(ws + VT_OFF);
  float* lp = (float*)(ws + L_OFF);
  float* opp = (float*)(ws + OP_OFF);
  float* outp = (float*)d_out;

  prep_w<<<384, 256, 0, stream>>>(Wq, Wk, Wv, wt);
  qkv_proj<<<512, 256, 0, stream>>>(x, wt, bq, bk, bv, qb, kb, vtb);
  attn<<<512, 256, 0, stream>>>(qb, kb, vtb, lp, opp);
  combine<<<256, 256, 0, stream>>>(opp, lp, outp);
}

// Round 5
// 131.284 us; speedup vs baseline: 1.4444x; 1.4444x over previous
//
#include <hip/hip_runtime.h>
#include <cstdint>

// Attention B=4, S=4096, WORD=512, ED=64, fp32 io. R5.
// R4's cooperative fusion never launched (runtime rejected grid); same
// structure as 4 plain dispatches: prep-W(frag-major) -> qkv(single barrier,
// contiguous 1KB W-frag loads) -> attn(LDS dbuf tiles, fast exp2, permlane
// P-exchange, Ksplit8) -> combine. Partials bf16, l fp32.

typedef __bf16 bf16x8 __attribute__((ext_vector_type(8)));
typedef float f32x4 __attribute__((ext_vector_type(4)));
typedef float f32x16 __attribute__((ext_vector_type(16)));
typedef int i32x2 __attribute__((ext_vector_type(2)));

#define SCALEQ 0.18033688011112042f  // log2(e)/sqrt(64)

// ws layout (bytes); total 23.86 MB
#define WT_OFF 0u          // bf16 Wt2 frag-major [12ntg][16kc][64lane][8]
#define Q_OFF  262144u     // bf16 Q [16384][64] (scaled)
#define K_OFF  2359296u    // bf16 K [16384][64]
#define VT_OFF 4456448u    // bf16 Vt [4][64][4096]
#define L_OFF  6553600u    // f32 l [8][16384]
#define OP_OFF 7077888u    // bf16 op [8][16384][64] = 16MB

#if defined(__has_builtin)
#if __has_builtin(__builtin_amdgcn_permlane32_swap)
#define HAVE_PLSWAP 1
#endif
#endif
#ifndef HAVE_PLSWAP
#define HAVE_PLSWAP 0
#endif

__device__ __forceinline__ unsigned short bf16_1(float a) {
  unsigned ua = __builtin_bit_cast(unsigned, a);
  ua += 0x7FFFu + ((ua >> 16) & 1u);
  return (unsigned short)(ua >> 16);
}
__device__ __forceinline__ unsigned pk_bf16(float a, float b) {
  unsigned ua = __builtin_bit_cast(unsigned, a);
  unsigned ub = __builtin_bit_cast(unsigned, b);
  ua += 0x7FFFu + ((ua >> 16) & 1u);
  ub += 0x7FFFu + ((ub >> 16) & 1u);
  return (ua >> 16) | (ub & 0xFFFF0000u);
}
// round-half-up bf16 pack (lo,hi): 2 adds + 1 v_perm
__device__ __forceinline__ unsigned pkru(float lo, float hi) {
  unsigned a = __builtin_bit_cast(unsigned, lo) + 0x8000u;
  unsigned b = __builtin_bit_cast(unsigned, hi) + 0x8000u;
  return __builtin_amdgcn_perm(b, a, 0x07060302u);
}
// x' = [x.lo32lanes | y.lo32lanes]; y' = [x.hi | y.hi]
__device__ __forceinline__ void plswap(unsigned& x, unsigned& y, unsigned hl) {
#if HAVE_PLSWAP
  i32x2 r = __builtin_amdgcn_permlane32_swap((int)x, (int)y, false, false);
  x = (unsigned)r[0];
  y = (unsigned)r[1];
#else
  unsigned xs = (unsigned)__shfl_xor((int)x, 32);
  unsigned ys = (unsigned)__shfl_xor((int)y, 32);
  unsigned nx = hl ? ys : x;
  unsigned ny = hl ? y : xs;
  x = nx;
  y = ny;
#endif
}

// ------------- kernel 0: W -> frag-major bf16 Wt2 --------------------------
__global__ __launch_bounds__(256) void prep_w(const float* __restrict__ Wq,
                                              const float* __restrict__ Wk,
                                              const float* __restrict__ Wv,
                                              unsigned short* __restrict__ wt2) {
  unsigned gtid = blockIdx.x * 256u + threadIdx.x;  // 98304
  unsigned mat = gtid >> 15, rem = gtid & 32767u;
  const float* w = (mat == 0) ? Wq : (mat == 1) ? Wk : Wv;
  float v = w[rem];  // coalesced [k][n]
  unsigned k = rem >> 6, n = rem & 63u;
  unsigned col = mat * 64u + n;
  unsigned ntg = col >> 4, l15c = col & 15u;
  unsigned kc = k >> 5, quad = (k >> 3) & 3u, j = k & 7u;
  wt2[((ntg * 16u + kc) * 64u + quad * 16u + l15c) * 8u + j] = bf16_1(v);
}

// ------------- kernel 1: QKV projection (32 rows/block, grid 512) ----------
__global__ __launch_bounds__(256, 2) void qkv_proj(
    const float* __restrict__ x, const unsigned short* __restrict__ wt2,
    const float* __restrict__ bq, const float* __restrict__ bk,
    const float* __restrict__ bv, unsigned short* __restrict__ qws,
    unsigned short* __restrict__ kws, unsigned short* __restrict__ vtws) {
  __shared__ __align__(16) char xs[32768];  // 32 rows x 512k bf16 swizzled
  __shared__ float biasl[192];
  const unsigned t = threadIdx.x;
  const unsigned row0 = blockIdx.x * 32u;
  const unsigned w = t >> 6, lane = t & 63u, l15 = lane & 15u, quad = lane >> 4;
  const unsigned rh = w & 1u, nh = w >> 1;

  if (t < 192u) {
    unsigned mat = t >> 6, n = t & 63u;
    biasl[t] = (mat == 0) ? bq[n] : (mat == 1) ? bk[n] : bv[n];
  }
#pragma unroll
  for (int i = 0; i < 16; i++) {  // stage x fp32 -> bf16, swizzled
    unsigned idx4 = t + 256u * (unsigned)i;
    unsigned fidx = idx4 * 4u;
    unsigned row = fidx >> 9, k = fidx & 511u, g = k >> 3;
    float4 f = *(const float4*)(x + row0 * 512u + fidx);
    int2 v = make_int2(pkru(f.x, f.y), pkru(f.z, f.w));
    *(int2*)(xs + row * 1024u + ((g ^ (row & 7u)) << 4) + (k & 7u) * 2u) = v;
  }
  __syncthreads();

  f32x4 acc[6];
#pragma unroll
  for (int i = 0; i < 6; i++) acc[i] = {0.f, 0.f, 0.f, 0.f};
  const unsigned arow = rh * 16u + l15;
  const unsigned short* wbase = wt2 + (nh * 6144u + lane) * 8u;

  int4 cur[6], nxt[6];
#pragma unroll
  for (int nt = 0; nt < 6; nt++)  // each frag load = 1KB fully contiguous
    cur[nt] = *(const int4*)(wbase + (unsigned)nt * 8192u);
  for (unsigned kc = 0; kc < 16u; kc++) {
    if (kc < 15u) {
#pragma unroll
      for (int nt = 0; nt < 6; nt++)
        nxt[nt] = *(const int4*)(wbase + ((unsigned)nt * 16u + kc + 1u) * 512u);
    }
    unsigned ag = kc * 4u + quad;
    int4 av = *(const int4*)(xs + arow * 1024u + ((ag ^ (arow & 7u)) << 4));
    bf16x8 a = __builtin_bit_cast(bf16x8, av);
#pragma unroll
    for (int nt = 0; nt < 6; nt++)
      acc[nt] = __builtin_amdgcn_mfma_f32_16x16x32_bf16(
          a, __builtin_bit_cast(bf16x8, cur[nt]), acc[nt], 0, 0, 0);
#pragma unroll
    for (int nt = 0; nt < 6; nt++) cur[nt] = nxt[nt];
  }
  unsigned sb = row0 + rh * 16u + quad * 4u;
  unsigned vb = sb >> 12, s = sb & 4095u;
#pragma unroll
  for (int nt = 0; nt < 6; nt++) {
    unsigned col = nh * 96u + (unsigned)nt * 16u + l15;
    unsigned mat = col >> 6, n = col & 63u;
    float bb = biasl[col];
    if (mat == 0) {
#pragma unroll
      for (int r = 0; r < 4; r++)
        qws[(sb + (unsigned)r) * 64u + n] = bf16_1((acc[nt][r] + bb) * SCALEQ);
    } else if (mat == 1) {
#pragma unroll
      for (int r = 0; r < 4; r++)
        kws[(sb + (unsigned)r) * 64u + n] = bf16_1(acc[nt][r] + bb);
    } else {
      int2 pv = make_int2(pk_bf16(acc[nt][0] + bb, acc[nt][1] + bb),
                          pk_bf16(acc[nt][2] + bb, acc[nt][3] + bb));
      *(int2*)(vtws + vb * 262144u + n * 4096u + s) = pv;
    }
  }
}

// ------------- kernel 2: flash attention (Ksplit 8, grid 512) --------------
// 512 = ks(8) x b(4) x qt(16 of 256q). 4 waves x 64q. 64-key dbuf LDS tiles.
__global__ __launch_bounds__(256, 2) void attn(
    const unsigned short* __restrict__ qws, const unsigned short* __restrict__ kws,
    const unsigned short* __restrict__ vtws, float* __restrict__ lws,
    unsigned short* __restrict__ opp) {
  __shared__ __align__(16) char sm[34816];
  const unsigned t = threadIdx.x;
  const unsigned w = t >> 6, lane = t & 63u, l31 = lane & 31u, hl = lane >> 5;
  const unsigned bid = blockIdx.x;
  const unsigned ks = bid >> 6;
  const unsigned b = (bid >> 4) & 3u;
  const unsigned qt = bid & 15u;
  const unsigned q0 = qt * 256u + w * 64u;
  const unsigned key0 = ks * 512u;

  bf16x8 qf[2][4];
#pragma unroll
  for (int qt2 = 0; qt2 < 2; qt2++)
#pragma unroll
    for (int kq = 0; kq < 4; kq++)
      qf[qt2][kq] = __builtin_bit_cast(
          bf16x8,
          *(const int4*)(qws + (b * 4096u + q0 + (unsigned)qt2 * 32u + l31) * 64u +
                         (unsigned)kq * 16u + hl * 8u));
  f32x16 accO[2][2];
#pragma unroll
  for (int i = 0; i < 2; i++)
#pragma unroll
    for (int j = 0; j < 2; j++)
#pragma unroll
      for (int r = 0; r < 16; r++) accO[i][j][r] = 0.f;
  float lsum[2] = {0.f, 0.f};

  const unsigned short* kg = kws + (b * 4096u + key0) * 64u;
  const unsigned short* vg = vtws + b * 262144u + key0;
  const unsigned r0s = t >> 3, g0s = t & 7u;
  const unsigned r1s = (t + 256u) >> 3, g1s = t & 7u;

  int4 stg[4];
#define LOADTILE(kt)                                                          \
  {                                                                           \
    stg[0] = *(const int4*)(kg + ((kt) * 64u + r0s) * 64u + g0s * 8u);        \
    stg[1] = *(const int4*)(kg + ((kt) * 64u + r1s) * 64u + g1s * 8u);        \
    stg[2] = *(const int4*)(vg + r0s * 4096u + (kt) * 64u + g0s * 8u);        \
    stg[3] = *(const int4*)(vg + r1s * 4096u + (kt) * 64u + g1s * 8u);        \
  }
#define WRITETILE(bi)                                                         \
  {                                                                           \
    char* base = sm + (bi) * 16384u;                                          \
    *(int4*)(base + r0s * 128u + ((g0s ^ (r0s & 7u)) << 4)) = stg[0];         \
    *(int4*)(base + r1s * 128u + ((g1s ^ (r1s & 7u)) << 4)) = stg[1];         \
    *(int4*)(base + 8192u + r0s * 128u + ((g0s ^ (r0s & 7u)) << 4)) = stg[2]; \
    *(int4*)(base + 8192u + r1s * 128u + ((g1s ^ (r1s & 7u)) << 4)) = stg[3]; \
  }
  LOADTILE(0u);
  WRITETILE(0u);
  __syncthreads();

  for (unsigned kt = 0; kt < 8u; kt++) {
    if (kt < 7u) LOADTILE(kt + 1u);
    char* kb_ = sm + (kt & 1u) * 16384u;
    char* vb_ = kb_ + 8192u;
    bf16x8 kf[2][4], vf[2][4];
#pragma unroll
    for (int kh = 0; kh < 2; kh++)
#pragma unroll
      for (int kq = 0; kq < 4; kq++) {
        unsigned row = (unsigned)kh * 32u + l31;
        kf[kh][kq] = __builtin_bit_cast(
            bf16x8, *(const int4*)(kb_ + row * 128u +
                                   ((((unsigned)kq * 2u + hl) ^ (row & 7u)) << 4)));
      }
#pragma unroll
    for (int dh = 0; dh < 2; dh++)
#pragma unroll
      for (int kqg = 0; kqg < 4; kqg++) {
        unsigned row = (unsigned)dh * 32u + l31;
        vf[dh][kqg] = __builtin_bit_cast(
            bf16x8, *(const int4*)(vb_ + row * 128u +
                                   ((((unsigned)kqg * 2u + hl) ^ (row & 7u)) << 4)));
      }
#pragma unroll
    for (int qt2 = 0; qt2 < 2; qt2++) {
      f32x16 s0, s1;
#pragma unroll
      for (int r = 0; r < 16; r++) { s0[r] = 0.f; s1[r] = 0.f; }
#pragma unroll
      for (int kq = 0; kq < 4; kq++) {
        s0 = __builtin_amdgcn_mfma_f32_32x32x16_bf16(kf[0][kq], qf[qt2][kq], s0, 0, 0, 0);
        s1 = __builtin_amdgcn_mfma_f32_32x32x16_bf16(kf[1][kq], qf[qt2][kq], s1, 0, 0, 0);
      }
      float lp = 0.f;
#pragma unroll
      for (int r = 0; r < 16; r++) {
        s0[r] = __builtin_amdgcn_exp2f(s0[r]);
        lp += s0[r];
        s1[r] = __builtin_amdgcn_exp2f(s1[r]);
        lp += s1[r];
      }
      lsum[qt2] += lp;
      unsigned pk[2][8];
#pragma unroll
      for (int c = 0; c < 4; c++) {
        pk[0][2 * c] = pkru(s0[4 * c + 0], s0[4 * c + 1]);
        pk[0][2 * c + 1] = pkru(s0[4 * c + 2], s0[4 * c + 3]);
        pk[1][2 * c] = pkru(s1[4 * c + 0], s1[4 * c + 1]);
        pk[1][2 * c + 1] = pkru(s1[4 * c + 2], s1[4 * c + 3]);
      }
#pragma unroll
      for (int kqg = 0; kqg < 4; kqg++) {
        int kh = kqg >> 1, kqpl = kqg & 1;
        unsigned a0 = pk[kh][4 * kqpl + 0], a1 = pk[kh][4 * kqpl + 1];
        unsigned b0 = pk[kh][4 * kqpl + 2], b1 = pk[kh][4 * kqpl + 3];
        plswap(a0, b0, hl);
        plswap(a1, b1, hl);
        int4 fr = make_int4((int)a0, (int)a1, (int)b0, (int)b1);
        bf16x8 pf = __builtin_bit_cast(bf16x8, fr);
#pragma unroll
        for (int dh = 0; dh < 2; dh++)
          accO[qt2][dh] = __builtin_amdgcn_mfma_f32_32x32x16_bf16(
              vf[dh][kqg], pf, accO[qt2][dh], 0, 0, 0);
      }
    }
    if (kt < 7u) {
      __syncthreads();
      WRITETILE((kt + 1u) & 1u);
      __syncthreads();
    }
  }
  // epilogue: l (fp32) + bf16 O-partials via wave-private LDS transpose
  __syncthreads();
  float* sc = (float*)(sm + w * 8704u);  // 32q x 68 floats
#pragma unroll
  for (int qt2 = 0; qt2 < 2; qt2++) {
    float lt = lsum[qt2] + __shfl_xor(lsum[qt2], 32);
    if (hl == 0u)
      lws[ks * 16384u + b * 4096u + q0 + (unsigned)qt2 * 32u + l31] = lt;
#pragma unroll
    for (int dh = 0; dh < 2; dh++)
#pragma unroll
      for (int r = 0; r < 16; r++) {
        unsigned d = (unsigned)dh * 32u + (unsigned)(r & 3) +
                     8u * (unsigned)(r >> 2) + 4u * hl;
        sc[l31 * 68u + d] = accO[qt2][dh][r];
      }
#pragma unroll
    for (int i = 0; i < 4; i++) {
      unsigned ql = (lane >> 3) + (unsigned)i * 8u;
      unsigned d0 = (lane & 7u) * 8u;
      float4 f0 = *(const float4*)(sc + ql * 68u + d0);
      float4 f1 = *(const float4*)(sc + ql * 68u + d0 + 4u);
      int4 pv = make_int4(pkru(f0.x, f0.y), pkru(f0.z, f0.w),
                          pkru(f1.x, f1.y), pkru(f1.z, f1.w));
      *(int4*)(opp + ks * 1048576u +
               (b * 4096u + q0 + (unsigned)qt2 * 32u + ql) * 64u + d0) = pv;
    }
  }
}

// ------------- kernel 3: combine 8 partials + normalize (grid 512) ---------
__global__ __launch_bounds__(256) void combine(const unsigned short* __restrict__ opp,
                                               const float* __restrict__ lws,
                                               float* __restrict__ out) {
#pragma unroll
  for (int ii = 0; ii < 2; ii++) {
    unsigned slot = blockIdx.x * 512u + threadIdx.x + 256u * (unsigned)ii;
    unsigned q = slot >> 4, c = (slot & 15u) * 4u;
    float l = 0.f;
#pragma unroll
    for (int s = 0; s < 8; s++) l += lws[(unsigned)s * 16384u + q];
    float inv = 1.0f / l;
    float4 r = make_float4(0.f, 0.f, 0.f, 0.f);
#pragma unroll
    for (int s = 0; s < 8; s++) {
      int2 pv = *(const int2*)(opp + (unsigned)s * 1048576u + q * 64u + c);
      r.x += __builtin_bit_cast(float, (unsigned)pv.x << 16);
      r.y += __builtin_bit_cast(float, (unsigned)pv.x & 0xFFFF0000u);
      r.z += __builtin_bit_cast(float, (unsigned)pv.y << 16);
      r.w += __builtin_bit_cast(float, (unsigned)pv.y & 0xFFFF0000u);
    }
    r.x *= inv; r.y *= inv; r.z *= inv; r.w *= inv;
    *(float4*)(out + q * 64u + c) = r;
  }
}

extern "C" void kernel_launch(void* const* d_in, const int* in_sizes, int n_in,
                              void* d_out, int out_size, void* d_ws,
                              size_t ws_size, hipStream_t stream) {
  const float* x = (const float*)d_in[0];
  const float* Wq = (const float*)d_in[1];
  const float* bq = (const float*)d_in[2];
  const float* Wk = (const float*)d_in[3];
  const float* bk = (const float*)d_in[4];
  const float* Wv = (const float*)d_in[5];
  const float* bv = (const float*)d_in[6];
  char* ws = (char*)d_ws;
  unsigned short* wt2 = (unsigned short*)(ws + WT_OFF);
  unsigned short* qb = (unsigned short*)(ws + Q_OFF);
  unsigned short* kb = (unsigned short*)(ws + K_OFF);
  unsigned short* vtb = (unsigned short*)(ws + VT_OFF);
  float* lp = (float*)(ws + L_OFF);
  unsigned short* opp = (unsigned short*)(ws + OP_OFF);
  float* outp = (float*)d_out;

  prep_w<<<384, 256, 0, stream>>>(Wq, Wk, Wv, wt2);
  qkv_proj<<<512, 256, 0, stream>>>(x, wt2, bq, bk, bv, qb, kb, vtb);
  attn<<<512, 256, 0, stream>>>(qb, kb, vtb, lp, opp);
  combine<<<512, 256, 0, stream>>>(opp, lp, outp);
}

// Round 6
// 127.817 us; speedup vs baseline: 1.4836x; 1.0271x over previous
//
#include <hip/hip_runtime.h>
#include <cstdint>

// Attention B=4, S=4096, WORD=512, ED=64, fp32 io. R6.
// Harness has ~50us fixed reset cost (256MB ws poison fill seen in rocprof);
// kernel sum ~80us vs ~20us roofline. This round: frag-major K/V global
// layout -> global_load_lds linear staging (no stg VGPRs, no LDS stores,
// 1 barrier/iter, conflict-free frag reads); attn 32q/wave @ 4 blocks/CU
// (grid 1024, launch_bounds(256,4)); qkv 16-row blocks grid 1024.

typedef __bf16 bf16x8 __attribute__((ext_vector_type(8)));
typedef float f32x4 __attribute__((ext_vector_type(4)));
typedef float f32x16 __attribute__((ext_vector_type(16)));
typedef int i32x2 __attribute__((ext_vector_type(2)));

#define SCALEQ 0.18033688011112042f  // log2(e)/sqrt(64)

// ws layout (bytes)
#define WT_OFF 0u          // bf16 Wt2 frag-major [12ntg][16kc][64lane][8]
#define Q_OFF  262144u     // bf16 Q [16384][64] (scaled)
#define KV_OFF 2359296u    // bf16 kv[256 tiles][8192]  (K chunks 0-7, V 8-15)
#define L_OFF  6553600u    // f32 l [8][16384]
#define OP_OFF 7077888u    // bf16 op [8][16384][64] = 16MB

#if defined(__has_builtin)
#if __has_builtin(__builtin_amdgcn_permlane32_swap)
#define HAVE_PLSWAP 1
#endif
#if __has_builtin(__builtin_amdgcn_global_load_lds)
#define HAVE_GLL 1
#endif
#endif
#ifndef HAVE_PLSWAP
#define HAVE_PLSWAP 0
#endif
#ifndef HAVE_GLL
#define HAVE_GLL 0
#endif

__device__ __forceinline__ unsigned short bf16_1(float a) {
  unsigned ua = __builtin_bit_cast(unsigned, a);
  ua += 0x7FFFu + ((ua >> 16) & 1u);
  return (unsigned short)(ua >> 16);
}
__device__ __forceinline__ unsigned pk_bf16(float a, float b) {
  unsigned ua = __builtin_bit_cast(unsigned, a);
  unsigned ub = __builtin_bit_cast(unsigned, b);
  ua += 0x7FFFu + ((ua >> 16) & 1u);
  ub += 0x7FFFu + ((ub >> 16) & 1u);
  return (ua >> 16) | (ub & 0xFFFF0000u);
}
__device__ __forceinline__ unsigned pkru(float lo, float hi) {
  unsigned a = __builtin_bit_cast(unsigned, lo) + 0x8000u;
  unsigned b = __builtin_bit_cast(unsigned, hi) + 0x8000u;
  return __builtin_amdgcn_perm(b, a, 0x07060302u);
}
__device__ __forceinline__ void plswap(unsigned& x, unsigned& y, unsigned hl) {
#if HAVE_PLSWAP
  i32x2 r = __builtin_amdgcn_permlane32_swap((int)x, (int)y, false, false);
  x = (unsigned)r[0];
  y = (unsigned)r[1];
#else
  unsigned xs = (unsigned)__shfl_xor((int)x, 32);
  unsigned ys = (unsigned)__shfl_xor((int)y, 32);
  unsigned nx = hl ? ys : x;
  unsigned ny = hl ? y : xs;
  x = nx;
  y = ny;
#endif
}
#if HAVE_GLL
__device__ __forceinline__ void gll16(const void* g, void* l) {
  __builtin_amdgcn_global_load_lds(
      (const __attribute__((address_space(1))) void*)g,
      (__attribute__((address_space(3))) void*)l, 16, 0, 0);
}
#endif

// ------------- kernel 0: W -> frag-major bf16 Wt2 --------------------------
__global__ __launch_bounds__(256) void prep_w(const float* __restrict__ Wq,
                                              const float* __restrict__ Wk,
                                              const float* __restrict__ Wv,
                                              unsigned short* __restrict__ wt2) {
  unsigned gtid = blockIdx.x * 256u + threadIdx.x;  // 98304
  unsigned mat = gtid >> 15, rem = gtid & 32767u;
  const float* w = (mat == 0) ? Wq : (mat == 1) ? Wk : Wv;
  float v = w[rem];  // coalesced [k][n]
  unsigned k = rem >> 6, n = rem & 63u;
  unsigned col = mat * 64u + n;
  unsigned ntg = col >> 4, l15c = col & 15u;
  unsigned kc = k >> 5, quad = (k >> 3) & 3u, j = k & 7u;
  wt2[((ntg * 16u + kc) * 64u + quad * 16u + l15c) * 8u + j] = bf16_1(v);
}

// ------------- kernel 1: QKV projection (16 rows/block, grid 1024) ---------
__global__ __launch_bounds__(256, 4) void qkv_proj(
    const float* __restrict__ x, const unsigned short* __restrict__ wt2,
    const float* __restrict__ bq, const float* __restrict__ bk,
    const float* __restrict__ bv, unsigned short* __restrict__ qws,
    unsigned short* __restrict__ kvws) {
  __shared__ __align__(16) char xs[16384];  // 16 rows x 512k bf16 swizzled
  __shared__ float biasl[192];
  const unsigned t = threadIdx.x;
  const unsigned row0 = blockIdx.x * 16u;
  const unsigned w = t >> 6, lane = t & 63u, l15 = lane & 15u, quad = lane >> 4;

  if (t < 192u) {
    unsigned mat = t >> 6, n = t & 63u;
    biasl[t] = (mat == 0) ? bq[n] : (mat == 1) ? bk[n] : bv[n];
  }
#pragma unroll
  for (int i = 0; i < 8; i++) {  // stage x fp32 -> bf16, swizzled
    unsigned idx4 = t + 256u * (unsigned)i;
    unsigned fidx = idx4 * 4u;
    unsigned row = fidx >> 9, k = fidx & 511u, g = k >> 3;
    float4 f = *(const float4*)(x + row0 * 512u + fidx);
    int2 v = make_int2(pkru(f.x, f.y), pkru(f.z, f.w));
    *(int2*)(xs + row * 1024u + ((g ^ (row & 7u)) << 4) + (k & 7u) * 2u) = v;
  }
  __syncthreads();

  f32x4 acc[3];
#pragma unroll
  for (int i = 0; i < 3; i++) acc[i] = {0.f, 0.f, 0.f, 0.f};
  const unsigned arow = l15;
  const unsigned short* wbase = wt2 + (w * 3u * 1024u + lane) * 8u;

  int4 cur[3], nxt[3];
#pragma unroll
  for (int nt = 0; nt < 3; nt++)  // each frag load = 1KB fully contiguous
    cur[nt] = *(const int4*)(wbase + (unsigned)nt * 8192u);
  for (unsigned kc = 0; kc < 16u; kc++) {
    if (kc < 15u) {
#pragma unroll
      for (int nt = 0; nt < 3; nt++)
        nxt[nt] = *(const int4*)(wbase + ((unsigned)nt * 16u + kc + 1u) * 512u);
    }
    unsigned ag = kc * 4u + quad;
    int4 av = *(const int4*)(xs + arow * 1024u + ((ag ^ (arow & 7u)) << 4));
    bf16x8 a = __builtin_bit_cast(bf16x8, av);
#pragma unroll
    for (int nt = 0; nt < 3; nt++)
      acc[nt] = __builtin_amdgcn_mfma_f32_16x16x32_bf16(
          a, __builtin_bit_cast(bf16x8, cur[nt]), acc[nt], 0, 0, 0);
#pragma unroll
    for (int nt = 0; nt < 3; nt++) cur[nt] = nxt[nt];
  }
  unsigned sb = row0 + quad * 4u;
#pragma unroll
  for (int nt = 0; nt < 3; nt++) {
    unsigned col = w * 48u + (unsigned)nt * 16u + l15;
    unsigned mat = col >> 6, n = col & 63u;
    float bb = biasl[col];
    if (mat == 0) {
#pragma unroll
      for (int r = 0; r < 4; r++)
        qws[(sb + (unsigned)r) * 64u + n] = bf16_1((acc[nt][r] + bb) * SCALEQ);
    } else if (mat == 1) {
      // K frag-major: kv[tile][n>>3][kappa][n&7], chunks 0..7
#pragma unroll
      for (int r = 0; r < 4; r++) {
        unsigned s = sb + (unsigned)r;
        unsigned bb2 = s >> 12, tile = (s & 4095u) >> 6, kap = s & 63u;
        kvws[(bb2 * 64u + tile) * 8192u + (n >> 3) * 512u + kap * 8u + (n & 7u)] =
            bf16_1(acc[nt][r] + bb);
      }
    } else {
      // V frag-major: kv[tile][8 + kg][d=n][kappa&7], chunks 8..15
      unsigned s = sb;
      unsigned bb2 = s >> 12, tile = (s & 4095u) >> 6;
      unsigned kg = (s & 63u) >> 3, j0 = s & 7u;  // j0 in {0,4}; r adds 0..3
      int2 pv = make_int2(pk_bf16(acc[nt][0] + bb, acc[nt][1] + bb),
                          pk_bf16(acc[nt][2] + bb, acc[nt][3] + bb));
      *(int2*)(kvws + (bb2 * 64u + tile) * 8192u + (8u + kg) * 512u + n * 8u +
               j0) = pv;
    }
  }
}

// ------------- kernel 2: flash attention (Ksplit 8, grid 1024) -------------
// 1024 = ks(8) x b(4) x qt(32 of 128q). 4 waves x 32q. 64-key dbuf tiles,
// global_load_lds linear staging, 1 barrier/iter.
__global__ __launch_bounds__(256, 4) void attn(
    const unsigned short* __restrict__ qws,
    const unsigned short* __restrict__ kvws, float* __restrict__ lws,
    unsigned short* __restrict__ opp) {
  __shared__ __align__(16) char sm[34816];  // dbuf 2x16KB; epilogue 4x8704
  const unsigned t = threadIdx.x;
  const unsigned w = t >> 6, lane = t & 63u, l31 = lane & 31u, hl = lane >> 5;
  const unsigned bid = blockIdx.x;
  const unsigned ks = bid >> 7;
  const unsigned b = (bid >> 5) & 3u;
  const unsigned qt = bid & 31u;
  const unsigned q0 = qt * 128u + w * 32u;
  const unsigned short* kvb = kvws + (b * 64u + ks * 8u) * 8192u + lane * 8u;

  bf16x8 qf[4];
#pragma unroll
  for (int kq = 0; kq < 4; kq++)
    qf[kq] = __builtin_bit_cast(
        bf16x8, *(const int4*)(qws + (b * 4096u + q0 + l31) * 64u +
                               (unsigned)kq * 16u + hl * 8u));
  f32x16 accO[2];
#pragma unroll
  for (int dh = 0; dh < 2; dh++)
#pragma unroll
    for (int r = 0; r < 16; r++) accO[dh][r] = 0.f;
  float lsum = 0.f;

#if HAVE_GLL
#define STAGE(kt_, bi_)                                                \
  {                                                                    \
    _Pragma("unroll") for (int i = 0; i < 4; i++) {                    \
      unsigned c = (unsigned)i * 4u + w;                               \
      gll16(kvb + (kt_)*8192u + c * 512u,                              \
            sm + (bi_)*16384u + c * 1024u + (w * 0u));                 \
    }                                                                  \
  }
  STAGE(0u, 0u);
  __syncthreads();
#else
  int4 stg[4];
#define LOADT(kt_)                                                       \
  {                                                                      \
    _Pragma("unroll") for (int i = 0; i < 4; i++) stg[i] =               \
        *(const int4*)(kvb + (kt_)*8192u + ((unsigned)i * 4u + w) * 512u); \
  }
#define WRITET(bi_)                                                       \
  {                                                                       \
    _Pragma("unroll") for (int i = 0; i < 4; i++)                         \
        *(int4*)(sm + (bi_)*16384u + ((unsigned)i * 4u + w) * 1024u +     \
                 lane * 16u - lane * 16u + lane * 16u) = stg[i];          \
  }
  LOADT(0u);
  {
#pragma unroll
    for (int i = 0; i < 4; i++)
      *(int4*)(sm + ((unsigned)i * 4u + w) * 1024u + lane * 16u) = stg[i];
  }
  __syncthreads();
#endif

  for (unsigned kt = 0; kt < 8u; kt++) {
#if HAVE_GLL
    if (kt < 7u) STAGE(kt + 1u, (kt + 1u) & 1u);
#else
    if (kt < 7u) LOADT(kt + 1u);
#endif
    char* kb = sm + (kt & 1u) * 16384u;
#pragma unroll
    for (int kh = 0; kh < 2; kh++) {
      f32x16 z;
#pragma unroll
      for (int r = 0; r < 16; r++) z[r] = 0.f;
#pragma unroll
      for (int kq = 0; kq < 4; kq++) {
        int4 kfr = *(const int4*)(kb + (((unsigned)kq * 2u + hl) * 64u +
                                        (unsigned)kh * 32u + l31) * 16u);
        z = __builtin_amdgcn_mfma_f32_32x32x16_bf16(
            __builtin_bit_cast(bf16x8, kfr), qf[kq], z, 0, 0, 0);
      }
      float lp = 0.f;
#pragma unroll
      for (int r = 0; r < 16; r++) {
        z[r] = __builtin_amdgcn_exp2f(z[r]);
        lp += z[r];
      }
      lsum += lp;
      unsigned pk8[8];
#pragma unroll
      for (int c2 = 0; c2 < 4; c2++) {
        pk8[2 * c2] = pkru(z[4 * c2 + 0], z[4 * c2 + 1]);
        pk8[2 * c2 + 1] = pkru(z[4 * c2 + 2], z[4 * c2 + 3]);
      }
#pragma unroll
      for (int kqpl = 0; kqpl < 2; kqpl++) {
        unsigned a0 = pk8[4 * kqpl + 0], a1 = pk8[4 * kqpl + 1];
        unsigned b0 = pk8[4 * kqpl + 2], b1 = pk8[4 * kqpl + 3];
        plswap(a0, b0, hl);
        plswap(a1, b1, hl);
        int4 fr = make_int4((int)a0, (int)a1, (int)b0, (int)b1);
        bf16x8 pf = __builtin_bit_cast(bf16x8, fr);
        unsigned kqg = (unsigned)kh * 2u + (unsigned)kqpl;
#pragma unroll
        for (int dh = 0; dh < 2; dh++) {
          int4 vfr = *(const int4*)(kb + 8192u + ((kqg * 2u + hl) * 64u +
                                                  (unsigned)dh * 32u + l31) * 16u);
          accO[dh] = __builtin_amdgcn_mfma_f32_32x32x16_bf16(
              __builtin_bit_cast(bf16x8, vfr), pf, accO[dh], 0, 0, 0);
        }
      }
    }
    __syncthreads();
#if !HAVE_GLL
    if (kt < 7u) {
#pragma unroll
      for (int i = 0; i < 4; i++)
        *(int4*)(sm + ((kt + 1u) & 1u) * 16384u +
                 ((unsigned)i * 4u + w) * 1024u + lane * 16u) = stg[i];
      __syncthreads();
    }
#endif
  }
  // epilogue: l + bf16 O-partials via wave-private LDS transpose
  float lt = lsum + __shfl_xor(lsum, 32);
  if (hl == 0u) lws[ks * 16384u + b * 4096u + q0 + l31] = lt;
  float* sc = (float*)(sm + w * 8704u);  // 32q x 68 floats
#pragma unroll
  for (int dh = 0; dh < 2; dh++)
#pragma unroll
    for (int r = 0; r < 16; r++) {
      unsigned d = (unsigned)dh * 32u + (unsigned)(r & 3) +
                   8u * (unsigned)(r >> 2) + 4u * hl;
      sc[l31 * 68u + d] = accO[dh][r];
    }
#pragma unroll
  for (int i = 0; i < 4; i++) {
    unsigned ql = (lane >> 3) + (unsigned)i * 8u;
    unsigned d0 = (lane & 7u) * 8u;
    float4 f0 = *(const float4*)(sc + ql * 68u + d0);
    float4 f1 = *(const float4*)(sc + ql * 68u + d0 + 4u);
    int4 pv = make_int4(pkru(f0.x, f0.y), pkru(f0.z, f0.w),
                        pkru(f1.x, f1.y), pkru(f1.z, f1.w));
    *(int4*)(opp + ks * 1048576u + (b * 4096u + q0 + ql) * 64u + d0) = pv;
  }
}

// ------------- kernel 3: combine 8 partials + normalize (grid 512) ---------
__global__ __launch_bounds__(256) void combine(const unsigned short* __restrict__ opp,
                                               const float* __restrict__ lws,
                                               float* __restrict__ out) {
#pragma unroll
  for (int ii = 0; ii < 2; ii++) {
    unsigned slot = blockIdx.x * 512u + threadIdx.x + 256u * (unsigned)ii;
    unsigned q = slot >> 4, c = (slot & 15u) * 4u;
    float l = 0.f;
#pragma unroll
    for (int s = 0; s < 8; s++) l += lws[(unsigned)s * 16384u + q];
    float inv = 1.0f / l;
    float4 r = make_float4(0.f, 0.f, 0.f, 0.f);
#pragma unroll
    for (int s = 0; s < 8; s++) {
      int2 pv = *(const int2*)(opp + (unsigned)s * 1048576u + q * 64u + c);
      r.x += __builtin_bit_cast(float, (unsigned)pv.x << 16);
      r.y += __builtin_bit_cast(float, (unsigned)pv.x & 0xFFFF0000u);
      r.z += __builtin_bit_cast(float, (unsigned)pv.y << 16);
      r.w += __builtin_bit_cast(float, (unsigned)pv.y & 0xFFFF0000u);
    }
    r.x *= inv; r.y *= inv; r.z *= inv; r.w *= inv;
    *(float4*)(out + q * 64u + c) = r;
  }
}

extern "C" void kernel_launch(void* const* d_in, const int* in_sizes, int n_in,
                              void* d_out, int out_size, void* d_ws,
                              size_t ws_size, hipStream_t stream) {
  const float* x = (const float*)d_in[0];
  const float* Wq = (const float*)d_in[1];
  const float* bq = (const float*)d_in[2];
  const float* Wk = (const float*)d_in[3];
  const float* bk = (const float*)d_in[4];
  const float* Wv = (const float*)d_in[5];
  const float* bv = (const float*)d_in[6];
  char* ws = (char*)d_ws;
  unsigned short* wt2 = (unsigned short*)(ws + WT_OFF);
  unsigned short* qb = (unsigned short*)(ws + Q_OFF);
  unsigned short* kvb = (unsigned short*)(ws + KV_OFF);
  float* lp = (float*)(ws + L_OFF);
  unsigned short* opp = (unsigned short*)(ws + OP_OFF);
  float* outp = (float*)d_out;

  prep_w<<<384, 256, 0, stream>>>(Wq, Wk, Wv, wt2);
  qkv_proj<<<1024, 256, 0, stream>>>(x, wt2, bq, bk, bv, qb, kvb);
  attn<<<1024, 256, 0, stream>>>(qb, kvb, lp, opp);
  combine<<<512, 256, 0, stream>>>(opp, lp, outp);
}

// Round 7
// 118.987 us; speedup vs baseline: 1.5937x; 1.0742x over previous
//
#include <hip/hip_runtime.h>
#include <cstdint>

// Attention B=4, S=4096, WORD=512, ED=64, fp32 io. R7.
// Fix R6's hidden serialization: global_load_lds was issued BEFORE the
// ds_reads of the current buffer; the waitcnt pass can't disprove aliasing
// and emits s_waitcnt vmcnt(0) before the reads -> every iter waited on the
// NEXT tile's DMA. R7: read all frags to VGPRs first, then issue DMA, then
// compute from regs only, then barrier. launch_bounds(256,3) for ~145 regs.

typedef __bf16 bf16x8 __attribute__((ext_vector_type(8)));
typedef float f32x4 __attribute__((ext_vector_type(4)));
typedef float f32x16 __attribute__((ext_vector_type(16)));
typedef int i32x2 __attribute__((ext_vector_type(2)));

#define SCALEQ 0.18033688011112042f  // log2(e)/sqrt(64)

// ws layout (bytes)
#define WT_OFF 0u          // bf16 Wt2 frag-major [12ntg][16kc][64lane][8]
#define Q_OFF  262144u     // bf16 Q [16384][64] (scaled)
#define KV_OFF 2359296u    // bf16 kv[256 tiles][8192]  (K chunks 0-7, V 8-15)
#define L_OFF  6553600u    // f32 l [8][16384]
#define OP_OFF 7077888u    // bf16 op [8][16384][64] = 16MB

#if defined(__has_builtin)
#if __has_builtin(__builtin_amdgcn_permlane32_swap)
#define HAVE_PLSWAP 1
#endif
#if __has_builtin(__builtin_amdgcn_global_load_lds)
#define HAVE_GLL 1
#endif
#endif
#ifndef HAVE_PLSWAP
#define HAVE_PLSWAP 0
#endif
#ifndef HAVE_GLL
#define HAVE_GLL 0
#endif

__device__ __forceinline__ unsigned short bf16_1(float a) {
  unsigned ua = __builtin_bit_cast(unsigned, a);
  ua += 0x7FFFu + ((ua >> 16) & 1u);
  return (unsigned short)(ua >> 16);
}
__device__ __forceinline__ unsigned pk_bf16(float a, float b) {
  unsigned ua = __builtin_bit_cast(unsigned, a);
  unsigned ub = __builtin_bit_cast(unsigned, b);
  ua += 0x7FFFu + ((ua >> 16) & 1u);
  ub += 0x7FFFu + ((ub >> 16) & 1u);
  return (ua >> 16) | (ub & 0xFFFF0000u);
}
__device__ __forceinline__ unsigned pkru(float lo, float hi) {
  unsigned a = __builtin_bit_cast(unsigned, lo) + 0x8000u;
  unsigned b = __builtin_bit_cast(unsigned, hi) + 0x8000u;
  return __builtin_amdgcn_perm(b, a, 0x07060302u);
}
__device__ __forceinline__ void plswap(unsigned& x, unsigned& y, unsigned hl) {
#if HAVE_PLSWAP
  i32x2 r = __builtin_amdgcn_permlane32_swap((int)x, (int)y, false, false);
  x = (unsigned)r[0];
  y = (unsigned)r[1];
#else
  unsigned xs = (unsigned)__shfl_xor((int)x, 32);
  unsigned ys = (unsigned)__shfl_xor((int)y, 32);
  unsigned nx = hl ? ys : x;
  unsigned ny = hl ? y : xs;
  x = nx;
  y = ny;
#endif
}
#if HAVE_GLL
__device__ __forceinline__ void gll16(const void* g, void* l) {
  __builtin_amdgcn_global_load_lds(
      (const __attribute__((address_space(1))) void*)g,
      (__attribute__((address_space(3))) void*)l, 16, 0, 0);
}
#endif

// ------------- kernel 0: W -> frag-major bf16 Wt2 --------------------------
__global__ __launch_bounds__(256) void prep_w(const float* __restrict__ Wq,
                                              const float* __restrict__ Wk,
                                              const float* __restrict__ Wv,
                                              unsigned short* __restrict__ wt2) {
  unsigned gtid = blockIdx.x * 256u + threadIdx.x;  // 98304
  unsigned mat = gtid >> 15, rem = gtid & 32767u;
  const float* w = (mat == 0) ? Wq : (mat == 1) ? Wk : Wv;
  float v = w[rem];  // coalesced [k][n]
  unsigned k = rem >> 6, n = rem & 63u;
  unsigned col = mat * 64u + n;
  unsigned ntg = col >> 4, l15c = col & 15u;
  unsigned kc = k >> 5, quad = (k >> 3) & 3u, j = k & 7u;
  wt2[((ntg * 16u + kc) * 64u + quad * 16u + l15c) * 8u + j] = bf16_1(v);
}

// ------------- kernel 1: QKV projection (16 rows/block, grid 1024) ---------
__global__ __launch_bounds__(256, 4) void qkv_proj(
    const float* __restrict__ x, const unsigned short* __restrict__ wt2,
    const float* __restrict__ bq, const float* __restrict__ bk,
    const float* __restrict__ bv, unsigned short* __restrict__ qws,
    unsigned short* __restrict__ kvws) {
  __shared__ __align__(16) char xs[16384];  // 16 rows x 512k bf16 swizzled
  __shared__ float biasl[192];
  const unsigned t = threadIdx.x;
  const unsigned row0 = blockIdx.x * 16u;
  const unsigned w = t >> 6, lane = t & 63u, l15 = lane & 15u, quad = lane >> 4;

  if (t < 192u) {
    unsigned mat = t >> 6, n = t & 63u;
    biasl[t] = (mat == 0) ? bq[n] : (mat == 1) ? bk[n] : bv[n];
  }
#pragma unroll
  for (int i = 0; i < 8; i++) {  // stage x fp32 -> bf16, swizzled
    unsigned idx4 = t + 256u * (unsigned)i;
    unsigned fidx = idx4 * 4u;
    unsigned row = fidx >> 9, k = fidx & 511u, g = k >> 3;
    float4 f = *(const float4*)(x + row0 * 512u + fidx);
    int2 v = make_int2(pkru(f.x, f.y), pkru(f.z, f.w));
    *(int2*)(xs + row * 1024u + ((g ^ (row & 7u)) << 4) + (k & 7u) * 2u) = v;
  }
  __syncthreads();

  f32x4 acc[3];
#pragma unroll
  for (int i = 0; i < 3; i++) acc[i] = {0.f, 0.f, 0.f, 0.f};
  const unsigned arow = l15;
  const unsigned short* wbase = wt2 + (w * 3u * 1024u + lane) * 8u;

  int4 cur[3], nxt[3];
#pragma unroll
  for (int nt = 0; nt < 3; nt++)  // each frag load = 1KB fully contiguous
    cur[nt] = *(const int4*)(wbase + (unsigned)nt * 8192u);
  for (unsigned kc = 0; kc < 16u; kc++) {
    if (kc < 15u) {
#pragma unroll
      for (int nt = 0; nt < 3; nt++)
        nxt[nt] = *(const int4*)(wbase + ((unsigned)nt * 16u + kc + 1u) * 512u);
    }
    unsigned ag = kc * 4u + quad;
    int4 av = *(const int4*)(xs + arow * 1024u + ((ag ^ (arow & 7u)) << 4));
    bf16x8 a = __builtin_bit_cast(bf16x8, av);
#pragma unroll
    for (int nt = 0; nt < 3; nt++)
      acc[nt] = __builtin_amdgcn_mfma_f32_16x16x32_bf16(
          a, __builtin_bit_cast(bf16x8, cur[nt]), acc[nt], 0, 0, 0);
#pragma unroll
    for (int nt = 0; nt < 3; nt++) cur[nt] = nxt[nt];
  }
  unsigned sb = row0 + quad * 4u;
#pragma unroll
  for (int nt = 0; nt < 3; nt++) {
    unsigned col = w * 48u + (unsigned)nt * 16u + l15;
    unsigned mat = col >> 6, n = col & 63u;
    float bb = biasl[col];
    if (mat == 0) {
#pragma unroll
      for (int r = 0; r < 4; r++)
        qws[(sb + (unsigned)r) * 64u + n] = bf16_1((acc[nt][r] + bb) * SCALEQ);
    } else if (mat == 1) {
      // K frag-major: kv[tile][n>>3][kappa][n&7], chunks 0..7
#pragma unroll
      for (int r = 0; r < 4; r++) {
        unsigned s = sb + (unsigned)r;
        unsigned bb2 = s >> 12, tile = (s & 4095u) >> 6, kap = s & 63u;
        kvws[(bb2 * 64u + tile) * 8192u + (n >> 3) * 512u + kap * 8u + (n & 7u)] =
            bf16_1(acc[nt][r] + bb);
      }
    } else {
      // V frag-major: kv[tile][8 + kg][d=n][kappa&7], chunks 8..15
      unsigned s = sb;
      unsigned bb2 = s >> 12, tile = (s & 4095u) >> 6;
      unsigned kg = (s & 63u) >> 3, j0 = s & 7u;
      int2 pv = make_int2(pk_bf16(acc[nt][0] + bb, acc[nt][1] + bb),
                          pk_bf16(acc[nt][2] + bb, acc[nt][3] + bb));
      *(int2*)(kvws + (bb2 * 64u + tile) * 8192u + (8u + kg) * 512u + n * 8u +
               j0) = pv;
    }
  }
}

// ------------- kernel 2: flash attention (Ksplit 8, grid 1024) -------------
// Per iter: ds_read ALL frags -> regs, THEN issue DMA prefetch, THEN compute
// from regs only, THEN one barrier. No LDS access after DMA issue => no
// conservative vmcnt(0) stall before the reads.
__global__ __launch_bounds__(256, 3) void attn(
    const unsigned short* __restrict__ qws,
    const unsigned short* __restrict__ kvws, float* __restrict__ lws,
    unsigned short* __restrict__ opp) {
  __shared__ __align__(16) char sm[34816];  // dbuf 2x16KB; epilogue 4x8704
  const unsigned t = threadIdx.x;
  const unsigned w = t >> 6, lane = t & 63u, l31 = lane & 31u, hl = lane >> 5;
  const unsigned bid = blockIdx.x;
  const unsigned ks = bid >> 7;
  const unsigned b = (bid >> 5) & 3u;
  const unsigned qt = bid & 31u;
  const unsigned q0 = qt * 128u + w * 32u;
  const unsigned short* kvb = kvws + (b * 64u + ks * 8u) * 8192u + lane * 8u;

  bf16x8 qf[4];
#pragma unroll
  for (int kq = 0; kq < 4; kq++)
    qf[kq] = __builtin_bit_cast(
        bf16x8, *(const int4*)(qws + (b * 4096u + q0 + l31) * 64u +
                               (unsigned)kq * 16u + hl * 8u));
  f32x16 accO[2];
#pragma unroll
  for (int dh = 0; dh < 2; dh++)
#pragma unroll
    for (int r = 0; r < 16; r++) accO[dh][r] = 0.f;
  float lsum = 0.f;

#if HAVE_GLL
#define STAGE(kt_, bi_)                                                \
  {                                                                    \
    _Pragma("unroll") for (int i = 0; i < 4; i++) {                    \
      unsigned c = (unsigned)i * 4u + w;                               \
      gll16(kvb + (kt_)*8192u + c * 512u, sm + (bi_)*16384u + c * 1024u); \
    }                                                                  \
  }
  STAGE(0u, 0u);
  __syncthreads();
#else
  int4 stg[4];
#define LOADT(kt_)                                                         \
  {                                                                        \
    _Pragma("unroll") for (int i = 0; i < 4; i++) stg[i] =                 \
        *(const int4*)(kvb + (kt_)*8192u + ((unsigned)i * 4u + w) * 512u); \
  }
  LOADT(0u);
  {
#pragma unroll
    for (int i = 0; i < 4; i++)
      *(int4*)(sm + ((unsigned)i * 4u + w) * 1024u + lane * 16u) = stg[i];
  }
  __syncthreads();
#endif

  for (unsigned kt = 0; kt < 8u; kt++) {
    char* kb = sm + (kt & 1u) * 16384u;
    // (1) all frag reads -> registers (before any new LDS-DMA issue)
    int4 kfr[8], vfr[8];
#pragma unroll
    for (int kq = 0; kq < 4; kq++)
#pragma unroll
      for (int kh = 0; kh < 2; kh++)
        kfr[kq * 2 + kh] = *(const int4*)(
            kb + (((unsigned)kq * 2u + hl) * 64u + (unsigned)kh * 32u + l31) * 16u);
#pragma unroll
    for (int kqg = 0; kqg < 4; kqg++)
#pragma unroll
      for (int dh = 0; dh < 2; dh++)
        vfr[kqg * 2 + dh] = *(const int4*)(
            kb + 8192u +
            (((unsigned)kqg * 2u + hl) * 64u + (unsigned)dh * 32u + l31) * 16u);
    // (2) prefetch next tile
#if HAVE_GLL
    if (kt < 7u) STAGE(kt + 1u, (kt + 1u) & 1u);
#else
    if (kt < 7u) LOADT(kt + 1u);
#endif
    // (3) compute entirely from registers
#pragma unroll
    for (int kh = 0; kh < 2; kh++) {
      f32x16 z;
#pragma unroll
      for (int r = 0; r < 16; r++) z[r] = 0.f;
#pragma unroll
      for (int kq = 0; kq < 4; kq++)
        z = __builtin_amdgcn_mfma_f32_32x32x16_bf16(
            __builtin_bit_cast(bf16x8, kfr[kq * 2 + kh]), qf[kq], z, 0, 0, 0);
      float lp = 0.f;
#pragma unroll
      for (int r = 0; r < 16; r++) {
        z[r] = __builtin_amdgcn_exp2f(z[r]);
        lp += z[r];
      }
      lsum += lp;
      unsigned pk8[8];
#pragma unroll
      for (int c2 = 0; c2 < 4; c2++) {
        pk8[2 * c2] = pkru(z[4 * c2 + 0], z[4 * c2 + 1]);
        pk8[2 * c2 + 1] = pkru(z[4 * c2 + 2], z[4 * c2 + 3]);
      }
#pragma unroll
      for (int kqpl = 0; kqpl < 2; kqpl++) {
        unsigned a0 = pk8[4 * kqpl + 0], a1 = pk8[4 * kqpl + 1];
        unsigned b0 = pk8[4 * kqpl + 2], b1 = pk8[4 * kqpl + 3];
        plswap(a0, b0, hl);
        plswap(a1, b1, hl);
        int4 fr = make_int4((int)a0, (int)a1, (int)b0, (int)b1);
        bf16x8 pf = __builtin_bit_cast(bf16x8, fr);
        unsigned kqg = (unsigned)kh * 2u + (unsigned)kqpl;
#pragma unroll
        for (int dh = 0; dh < 2; dh++)
          accO[dh] = __builtin_amdgcn_mfma_f32_32x32x16_bf16(
              __builtin_bit_cast(bf16x8, vfr[kqg * 2u + (unsigned)dh]), pf,
              accO[dh], 0, 0, 0);
      }
    }
    // (4) barrier (drains DMA; overlapped by the compute above)
    __syncthreads();
#if !HAVE_GLL
    if (kt < 7u) {
#pragma unroll
      for (int i = 0; i < 4; i++)
        *(int4*)(sm + ((kt + 1u) & 1u) * 16384u +
                 ((unsigned)i * 4u + w) * 1024u + lane * 16u) = stg[i];
      __syncthreads();
    }
#endif
  }
  // epilogue: l + bf16 O-partials via wave-private LDS transpose
  float lt = lsum + __shfl_xor(lsum, 32);
  if (hl == 0u) lws[ks * 16384u + b * 4096u + q0 + l31] = lt;
  float* sc = (float*)(sm + w * 8704u);  // 32q x 68 floats
#pragma unroll
  for (int dh = 0; dh < 2; dh++)
#pragma unroll
    for (int r = 0; r < 16; r++) {
      unsigned d = (unsigned)dh * 32u + (unsigned)(r & 3) +
                   8u * (unsigned)(r >> 2) + 4u * hl;
      sc[l31 * 68u + d] = accO[dh][r];
    }
#pragma unroll
  for (int i = 0; i < 4; i++) {
    unsigned ql = (lane >> 3) + (unsigned)i * 8u;
    unsigned d0 = (lane & 7u) * 8u;
    float4 f0 = *(const float4*)(sc + ql * 68u + d0);
    float4 f1 = *(const float4*)(sc + ql * 68u + d0 + 4u);
    int4 pv = make_int4(pkru(f0.x, f0.y), pkru(f0.z, f0.w),
                        pkru(f1.x, f1.y), pkru(f1.z, f1.w));
    *(int4*)(opp + ks * 1048576u + (b * 4096u + q0 + ql) * 64u + d0) = pv;
  }
}

// ------------- kernel 3: combine 8 partials + normalize (grid 512) ---------
__global__ __launch_bounds__(256) void combine(const unsigned short* __restrict__ opp,
                                               const float* __restrict__ lws,
                                               float* __restrict__ out) {
#pragma unroll
  for (int ii = 0; ii < 2; ii++) {
    unsigned slot = blockIdx.x * 512u + threadIdx.x + 256u * (unsigned)ii;
    unsigned q = slot >> 4, c = (slot & 15u) * 4u;
    float l = 0.f;
#pragma unroll
    for (int s = 0; s < 8; s++) l += lws[(unsigned)s * 16384u + q];
    float inv = 1.0f / l;
    float4 r = make_float4(0.f, 0.f, 0.f, 0.f);
#pragma unroll
    for (int s = 0; s < 8; s++) {
      int2 pv = *(const int2*)(opp + (unsigned)s * 1048576u + q * 64u + c);
      r.x += __builtin_bit_cast(float, (unsigned)pv.x << 16);
      r.y += __builtin_bit_cast(float, (unsigned)pv.x & 0xFFFF0000u);
      r.z += __builtin_bit_cast(float, (unsigned)pv.y << 16);
      r.w += __builtin_bit_cast(float, (unsigned)pv.y & 0xFFFF0000u);
    }
    r.x *= inv; r.y *= inv; r.z *= inv; r.w *= inv;
    *(float4*)(out + q * 64u + c) = r;
  }
}

extern "C" void kernel_launch(void* const* d_in, const int* in_sizes, int n_in,
                              void* d_out, int out_size, void* d_ws,
                              size_t ws_size, hipStream_t stream) {
  const float* x = (const float*)d_in[0];
  const float* Wq = (const float*)d_in[1];
  const float* bq = (const float*)d_in[2];
  const float* Wk = (const float*)d_in[3];
  const float* bk = (const float*)d_in[4];
  const float* Wv = (const float*)d_in[5];
  const float* bv = (const float*)d_in[6];
  char* ws = (char*)d_ws;
  unsigned short* wt2 = (unsigned short*)(ws + WT_OFF);
  unsigned short* qb = (unsigned short*)(ws + Q_OFF);
  unsigned short* kvb = (unsigned short*)(ws + KV_OFF);
  float* lp = (float*)(ws + L_OFF);
  unsigned short* opp = (unsigned short*)(ws + OP_OFF);
  float* outp = (float*)d_out;

  prep_w<<<384, 256, 0, stream>>>(Wq, Wk, Wv, wt2);
  qkv_proj<<<1024, 256, 0, stream>>>(x, wt2, bq, bk, bv, qb, kvb);
  attn<<<1024, 256, 0, stream>>>(qb, kvb, lp, opp);
  combine<<<512, 256, 0, stream>>>(opp, lp, outp);
}